// Round 11
// baseline (240.377 us; speedup 1.0000x reference)
//
#include <hip/hip_runtime.h>
#include <hip/hip_bf16.h>
#include <hip/hip_fp16.h>
#include <math.h>

// ---------------------------------------------------------------------------
// SLADGNN round 11: round-10 + wider gather ILP.
// fp8(e5m2) rows; agg128 now 8 lanes x uint4 (8 edges in flight),
// agg64 now 4 lanes x uint4 (16 edges in flight; mean degree=16 -> 1 iter).
// ---------------------------------------------------------------------------

typedef __attribute__((ext_vector_type(8))) short short8;
typedef __attribute__((ext_vector_type(4))) float f32x4;

#define BKT_SHIFT 5
#define BKT_NODES 32
#define EPB 2048        // edges per sort_local block (391 blocks)
#define LCAP 1024       // per-bucket CSR slot capacity (mean 512, +22 sigma)
#define PREPN 28672     // prep_w elements
#define PREPB 112       // prep_w blocks

__device__ __forceinline__ short f2bs(float x) {
    __hip_bfloat16 b = __float2bfloat16(x);
    return *reinterpret_cast<short*>(&b);
}
__device__ __forceinline__ float2 bpair(unsigned u) {
    float lo = __uint_as_float(u << 16);
    float hi = __uint_as_float(u & 0xffff0000u);
    return make_float2(lo, hi);
}
__device__ __forceinline__ unsigned packbf(float a, float b) {
    unsigned la = (unsigned)(unsigned short)f2bs(a);
    unsigned hb = (unsigned)(unsigned short)f2bs(b);
    return la | (hb << 16);
}

// ---- e5m2 helpers: e5m2 byte == high byte of f16 --------------------------
__device__ __forceinline__ unsigned short enc2_e5m2(float a, float b) {
    unsigned ua = __half_as_ushort(__float2half(a));
    unsigned ub = __half_as_ushort(__float2half(b));
    ua = (ua + 0x80u) >> 8;          // round-half-up on dropped byte
    ub = (ub + 0x80u) >> 8;
    return (unsigned short)((ua & 0xffu) | ((ub & 0xffu) << 8));
}
__device__ __forceinline__ __half2 dec2lo(unsigned u) {
    unsigned h = ((u & 0xffu) << 8) | ((u & 0xff00u) << 16);
    return *reinterpret_cast<__half2*>(&h);
}
__device__ __forceinline__ __half2 dec2hi(unsigned u) {
    unsigned h = ((u >> 8) & 0xff00u) | (u & 0xff000000u);
    return *reinterpret_cast<__half2*>(&h);
}
__device__ __forceinline__ __half2 h2shfl_xor(__half2 h, int m) {
    int i = *reinterpret_cast<int*>(&h);
    i = __shfl_xor(i, m, 64);
    return *reinterpret_cast<__half2*>(&i);
}

// Block-wide exclusive scan of arr[0..n) in LDS. 2 barriers per 256-chunk.
__device__ __forceinline__ void block_excl_scan(int* __restrict__ arr, int n, int t) {
    __shared__ int wsums[4];
    int lane = t & 63, wv = t >> 6;
    int carry = 0;
    for (int c0 = 0; c0 < n; c0 += 256) {
        int i = c0 + t;
        int v = (i < n) ? arr[i] : 0;
        int orig = v;
#pragma unroll
        for (int off = 1; off < 64; off <<= 1) {
            int u = __shfl_up(v, off, 64);
            if (lane >= off) v += u;
        }
        if (lane == 63) wsums[wv] = v;
        __syncthreads();
        int w0 = wsums[0], w1 = wsums[1], w2 = wsums[2], w3 = wsums[3];
        int woff = (wv > 0 ? w0 : 0) + (wv > 1 ? w1 : 0) + (wv > 2 ? w2 : 0);
        int tot = w0 + w1 + w2 + w3;
        __syncthreads();
        if (i < n) arr[i] = carry + woff + (v - orig);
        carry += tot;
    }
}

// --------------------- K1: sort_local || prep W1/W2/W3 ---------------------

__global__ __launch_bounds__(256) void sort_local_kernel(const int* __restrict__ ei, int E,
                                                         int NB, int B,
                                                         int* __restrict__ glens,
                                                         int* __restrict__ gstart,
                                                         int* __restrict__ edge_sorted,
                                                         const float* __restrict__ W1,
                                                         const float* __restrict__ W2,
                                                         const float* __restrict__ W3,
                                                         __hip_bfloat16* __restrict__ Wp1,
                                                         __hip_bfloat16* __restrict__ Wp2,
                                                         __hip_bfloat16* __restrict__ Wp3) {
    int t = threadIdx.x;
    if ((int)blockIdx.x >= B) {
        int i = ((int)blockIdx.x - B) * 256 + t;
        if (i < 16384) {                      // W1: 128x128
            int k = i >> 7, n = i & 127;
            Wp1[(((k >> 3) * 128) + n) * 8 + (k & 7)] = __float2bfloat16(W1[i]);
        } else if (i < 24576) {               // W2: 128x64
            int j = i - 16384;
            int k = j >> 6, n = j & 63;
            Wp2[(((k >> 3) * 64) + n) * 8 + (k & 7)] = __float2bfloat16(W2[j]);
        } else if (i < PREPN) {               // W3: 64x64
            int j = i - 24576;
            int k = j >> 6, n = j & 63;
            Wp3[(((k >> 3) * 64) + n) * 8 + (k & 7)] = __float2bfloat16(W3[j]);
        }
        return;
    }
    extern __shared__ int lds[];
    int* hist  = lds;                 // NB
    int* lbase = lds + NB;            // NB
    int* sortd = lds + 2 * NB;        // EPB
    int blk = blockIdx.x;
    int e0 = blk * EPB;
    int cnt = E - e0;
    if (cnt > EPB) cnt = EPB;

    for (int i = t; i < NB; i += 256) hist[i] = 0;
    __syncthreads();
    for (int i = t; i < cnt; i += 256) {
        int dst = ei[E + e0 + i];
        atomicAdd(&hist[dst >> BKT_SHIFT], 1);
    }
    __syncthreads();
    for (int i = t; i < NB; i += 256) lbase[i] = hist[i];
    __syncthreads();
    block_excl_scan(lbase, NB, t);
    __syncthreads();
    for (int i = t; i < NB; i += 256) {
        glens[(size_t)blk * NB + i] = hist[i];
        gstart[(size_t)blk * NB + i] = lbase[i];
    }
    __syncthreads();
    for (int i = t; i < cnt; i += 256) {
        int src = ei[e0 + i];
        int dst = ei[E + e0 + i];
        int pos = atomicAdd(&lbase[dst >> BKT_SHIFT], 1);
        sortd[pos] = (src << BKT_SHIFT) | (dst & (BKT_NODES - 1));
    }
    __syncthreads();
    for (int i = t; i < cnt; i += 256) edge_sorted[e0 + i] = sortd[i];
}

// --------------------- K2: csr_build || gemm1 (disjoint block ranges) ------
// gemm1 stores T1 as e5m2 bytes (unscaled).

__global__ __launch_bounds__(256) void csr_gemm1_kernel(const int* __restrict__ edge_sorted,
                                                        const int* __restrict__ glens,
                                                        const int* __restrict__ gstart,
                                                        int NB, int B, int N,
                                                        int* __restrict__ row_beg,
                                                        int* __restrict__ row_end,
                                                        float* __restrict__ dinv,
                                                        int* __restrict__ csr,
                                                        const float* __restrict__ X,
                                                        const __hip_bfloat16* __restrict__ Wp1,
                                                        unsigned char* __restrict__ T1) {
    int t = threadIdx.x;
    if ((int)blockIdx.x >= NB) {
        int bid = (int)blockIdx.x - NB;
        int lane = t & 63;
        int wave = t >> 6;
        int q = lane >> 4, l16 = lane & 15;
        int rbase = bid * 64 + wave * 16;
        int row = rbase + l16;
        int rowc = row < N ? row : N - 1;
        f32x4 acc[8];
#pragma unroll
        for (int i = 0; i < 8; ++i) acc[i] = (f32x4){0.f, 0.f, 0.f, 0.f};
#pragma unroll
        for (int kt = 0; kt < 4; ++kt) {
            int k0 = kt * 32 + q * 8;
            const float* ap = X + (size_t)rowc * 128 + k0;
            float4 lo = *(const float4*)ap;
            float4 hi = *(const float4*)(ap + 4);
            short8 afrag;
            afrag[0] = f2bs(lo.x); afrag[1] = f2bs(lo.y);
            afrag[2] = f2bs(lo.z); afrag[3] = f2bs(lo.w);
            afrag[4] = f2bs(hi.x); afrag[5] = f2bs(hi.y);
            afrag[6] = f2bs(hi.z); afrag[7] = f2bs(hi.w);
            const short8* wrow = (const short8*)(Wp1 + (size_t)(kt * 4 + q) * 128 * 8);
#pragma unroll
            for (int tt = 0; tt < 8; ++tt) {
                short8 bfrag = wrow[tt * 16 + l16];
                acc[tt] = __builtin_amdgcn_mfma_f32_16x16x32_bf16(afrag, bfrag, acc[tt], 0, 0, 0);
            }
        }
#pragma unroll
        for (int r = 0; r < 4; ++r) {
            int gr = rbase + q * 4 + r;
#pragma unroll
            for (int tt = 0; tt < 8; ++tt) {
                float v = acc[tt][r];
                float p = __shfl_xor(v, 1, 64);
                if (((l16 & 1) == 0) && gr < N)
                    *(unsigned short*)(T1 + (size_t)gr * 128 + tt * 16 + l16) = enc2_e5m2(v, p);
            }
        }
        return;
    }
    // ---- csr_build ----
    __shared__ int lruns[512];
    __shared__ int loffs[512];
    __shared__ int sdeg[BKT_NODES];
    __shared__ int scur[BKT_NODES];
    __shared__ int raw[LCAP];
    __shared__ int srt[LCAP];
    int b = blockIdx.x;

    for (int i = t; i < 512; i += 256) {
        int v = (i < B) ? glens[(size_t)i * NB + b] : 0;
        lruns[i] = v;
        loffs[i] = v;
    }
    if (t < BKT_NODES) sdeg[t] = 0;
    __syncthreads();
    block_excl_scan(loffs, B, t);
    __syncthreads();
    int cnt = loffs[B - 1] + lruns[B - 1];
    if (cnt > LCAP) cnt = LCAP;

    for (int r = t; r < B; r += 256) {
        int len = lruns[r];
        if (len) {
            int off = loffs[r];
            int st = r * EPB + gstart[(size_t)r * NB + b];
            for (int k = 0; k < len; ++k) {
                int p = off + k;
                if (p < LCAP) raw[p] = edge_sorted[st + k];
            }
        }
    }
    __syncthreads();
    for (int i = t; i < cnt; i += 256) atomicAdd(&sdeg[raw[i] & (BKT_NODES - 1)], 1);
    __syncthreads();
    int base = b * LCAP;
    if (t < BKT_NODES) {
        int ssum = 0;
        for (int i = 0; i < t; ++i) ssum += sdeg[i];
        scur[t] = ssum;
        int node = b * BKT_NODES + t;
        if (node < N) {
            row_beg[node] = base + ssum;
            row_end[node] = base + ssum + sdeg[t];
            dinv[node] = rsqrtf((float)(sdeg[t] + 1));   // +1 self loop
        }
    }
    __syncthreads();
    for (int i = t; i < cnt; i += 256) {
        int p = raw[i];
        int pos = atomicAdd(&scur[p & (BKT_NODES - 1)], 1);
        srt[pos] = p >> BKT_SHIFT;
    }
    __syncthreads();
    for (int i = t; i < cnt; i += 256) csr[base + i] = srt[i];
}

// --------------------------- MFMA GEMM (fp8 out, prescaled) ----------------

template <int DI, int DO>
__global__ __launch_bounds__(256) void mfma_gemm_kernel(const __hip_bfloat16* __restrict__ A,
                                                        const __hip_bfloat16* __restrict__ Wp,
                                                        const float* __restrict__ dinv,
                                                        unsigned char* __restrict__ C, int N) {
    constexpr int NT = DO / 16;
    int t = threadIdx.x;
    int wave = t >> 6, lane = t & 63;
    int q = lane >> 4, l16 = lane & 15;
    int rbase = blockIdx.x * 64 + wave * 16;
    int row = rbase + l16;
    int rowc = row < N ? row : N - 1;

    f32x4 acc[NT];
#pragma unroll
    for (int i = 0; i < NT; ++i) acc[i] = (f32x4){0.f, 0.f, 0.f, 0.f};

#pragma unroll
    for (int kt = 0; kt < DI / 32; ++kt) {
        int k0 = kt * 32 + q * 8;
        short8 afrag = *(const short8*)(A + (size_t)rowc * DI + k0);
        const short8* wrow = (const short8*)(Wp + (size_t)(kt * 4 + q) * DO * 8);
#pragma unroll
        for (int tt = 0; tt < NT; ++tt) {
            short8 bfrag = wrow[tt * 16 + l16];
            acc[tt] = __builtin_amdgcn_mfma_f32_16x16x32_bf16(afrag, bfrag, acc[tt], 0, 0, 0);
        }
    }
#pragma unroll
    for (int r = 0; r < 4; ++r) {
        int gr = rbase + q * 4 + r;
        float dv = dinv[gr < N ? gr : 0];
#pragma unroll
        for (int tt = 0; tt < NT; ++tt) {
            float v = acc[tt][r] * dv;
            float p = __shfl_xor(v, 1, 64);
            if (((l16 & 1) == 0) && gr < N)
                *(unsigned short*)(C + (size_t)gr * DO + tt * 16 + l16) = enc2_e5m2(v, p);
        }
    }
}

// --------------------------- aggregation (fp8, wide ILP) -------------------

// D=128 e5m2 rows (128B), UNSCALED. 8 lanes x uint4/row -> 8 edges in flight.
__global__ __launch_bounds__(256) void agg128_kernel(const uint4* __restrict__ tmp,
                                                     const float* __restrict__ bias,
                                                     const float* __restrict__ dinv,
                                                     const int* __restrict__ row_beg,
                                                     const int* __restrict__ row_end,
                                                     const int* __restrict__ csr_src,
                                                     uint4* __restrict__ outp, int N) {
    int lane = threadIdx.x & 63;
    int oct = lane >> 3, sub = lane & 7;
    int node = blockIdx.x * 4 + (threadIdx.x >> 6);
    if (node >= N) return;
    float dvi = dinv[node];
    __half2 c[8];
#pragma unroll
    for (int i = 0; i < 8; ++i) c[i] = __float2half2_rn(0.f);
    if (oct == 0) {
        uint4 sv = tmp[(size_t)node * 8 + sub];
        __half2 dv2 = __float2half2_rn(dvi);
        c[0] = __hmul2(dec2lo(sv.x), dv2); c[1] = __hmul2(dec2hi(sv.x), dv2);
        c[2] = __hmul2(dec2lo(sv.y), dv2); c[3] = __hmul2(dec2hi(sv.y), dv2);
        c[4] = __hmul2(dec2lo(sv.z), dv2); c[5] = __hmul2(dec2hi(sv.z), dv2);
        c[6] = __hmul2(dec2lo(sv.w), dv2); c[7] = __hmul2(dec2hi(sv.w), dv2);
    }
    int beg = row_beg[node], end = row_end[node];
    for (int j = beg; j < end; j += 64) {
        int m = end - j;
        if (m > 64) m = 64;
        int s = 0;
        float dv = 0.0f;
        if (lane < m) { s = csr_src[j + lane]; dv = dinv[s]; }
        int iters = (m + 7) >> 3;
        for (int k = 0; k < iters; ++k) {
            int e = 8 * k + oct;
            int ec = (e < m) ? e : 0;
            int sk = __shfl(s, ec, 64);
            float dkf = __shfl(dv, ec, 64);
            uint4 v = tmp[(size_t)sk * 8 + sub];
            __half2 dk2 = __float2half2_rn((e < m) ? dkf : 0.0f);
            c[0] = __hfma2(dec2lo(v.x), dk2, c[0]); c[1] = __hfma2(dec2hi(v.x), dk2, c[1]);
            c[2] = __hfma2(dec2lo(v.y), dk2, c[2]); c[3] = __hfma2(dec2hi(v.y), dk2, c[3]);
            c[4] = __hfma2(dec2lo(v.z), dk2, c[4]); c[5] = __hfma2(dec2hi(v.z), dk2, c[5]);
            c[6] = __hfma2(dec2lo(v.w), dk2, c[6]); c[7] = __hfma2(dec2hi(v.w), dk2, c[7]);
        }
    }
#pragma unroll
    for (int off = 8; off <= 32; off <<= 1) {
#pragma unroll
        for (int i = 0; i < 8; ++i) c[i] = __hadd2(c[i], h2shfl_xor(c[i], off));
    }
    if (oct == 0) {
        // lane sub holds features [sub*16, sub*16+16)
        float2 f[8];
#pragma unroll
        for (int i = 0; i < 8; ++i) f[i] = __half22float2(c[i]);
        const float* bp = &bias[sub * 16];
        uint4 o1, o2;
        o1.x = packbf(fmaxf(dvi * f[0].x + bp[0], 0.f),  fmaxf(dvi * f[0].y + bp[1], 0.f));
        o1.y = packbf(fmaxf(dvi * f[1].x + bp[2], 0.f),  fmaxf(dvi * f[1].y + bp[3], 0.f));
        o1.z = packbf(fmaxf(dvi * f[2].x + bp[4], 0.f),  fmaxf(dvi * f[2].y + bp[5], 0.f));
        o1.w = packbf(fmaxf(dvi * f[3].x + bp[6], 0.f),  fmaxf(dvi * f[3].y + bp[7], 0.f));
        o2.x = packbf(fmaxf(dvi * f[4].x + bp[8], 0.f),  fmaxf(dvi * f[4].y + bp[9], 0.f));
        o2.y = packbf(fmaxf(dvi * f[5].x + bp[10], 0.f), fmaxf(dvi * f[5].y + bp[11], 0.f));
        o2.z = packbf(fmaxf(dvi * f[6].x + bp[12], 0.f), fmaxf(dvi * f[6].y + bp[13], 0.f));
        o2.w = packbf(fmaxf(dvi * f[7].x + bp[14], 0.f), fmaxf(dvi * f[7].y + bp[15], 0.f));
        outp[(size_t)node * 16 + sub * 2] = o1;
        outp[(size_t)node * 16 + sub * 2 + 1] = o2;
    }
}

// D=64 e5m2 rows (64B), PRESCALED. 4 lanes x uint4/row -> 16 edges in flight.
__global__ __launch_bounds__(256) void agg64_kernel(const uint4* __restrict__ tmp,
                                                    const float* __restrict__ bias,
                                                    const float* __restrict__ dinv,
                                                    const int* __restrict__ row_beg,
                                                    const int* __restrict__ row_end,
                                                    const int* __restrict__ csr_src,
                                                    uint4* __restrict__ outp, int N) {
    int lane = threadIdx.x & 63;
    int hex = lane >> 2, sub = lane & 3;
    int node = blockIdx.x * 4 + (threadIdx.x >> 6);
    if (node >= N) return;
    float dvi = dinv[node];
    __half2 one2 = __float2half2_rn(1.f);
    __half2 zero2 = __float2half2_rn(0.f);
    __half2 c[8];
#pragma unroll
    for (int i = 0; i < 8; ++i) c[i] = zero2;
    if (hex == 0) {
        uint4 sv = tmp[(size_t)node * 4 + sub];
        c[0] = dec2lo(sv.x); c[1] = dec2hi(sv.x);
        c[2] = dec2lo(sv.y); c[3] = dec2hi(sv.y);
        c[4] = dec2lo(sv.z); c[5] = dec2hi(sv.z);
        c[6] = dec2lo(sv.w); c[7] = dec2hi(sv.w);
    }
    int beg = row_beg[node], end = row_end[node];
    for (int j = beg; j < end; j += 64) {
        int m = end - j;
        if (m > 64) m = 64;
        int s = (lane < m) ? csr_src[j + lane] : 0;
        int iters = (m + 15) >> 4;
        for (int k = 0; k < iters; ++k) {
            int e = 16 * k + hex;
            int ec = (e < m) ? e : 0;
            int sk = __shfl(s, ec, 64);
            uint4 v = tmp[(size_t)sk * 4 + sub];
            __half2 dk2 = (e < m) ? one2 : zero2;
            c[0] = __hfma2(dec2lo(v.x), dk2, c[0]); c[1] = __hfma2(dec2hi(v.x), dk2, c[1]);
            c[2] = __hfma2(dec2lo(v.y), dk2, c[2]); c[3] = __hfma2(dec2hi(v.y), dk2, c[3]);
            c[4] = __hfma2(dec2lo(v.z), dk2, c[4]); c[5] = __hfma2(dec2hi(v.z), dk2, c[5]);
            c[6] = __hfma2(dec2lo(v.w), dk2, c[6]); c[7] = __hfma2(dec2hi(v.w), dk2, c[7]);
        }
    }
#pragma unroll
    for (int off = 4; off <= 32; off <<= 1) {
#pragma unroll
        for (int i = 0; i < 8; ++i) c[i] = __hadd2(c[i], h2shfl_xor(c[i], off));
    }
    if (hex == 0) {
        // lane sub holds features [sub*16, sub*16+16)
        float2 f[8];
#pragma unroll
        for (int i = 0; i < 8; ++i) f[i] = __half22float2(c[i]);
        const float* bp = &bias[sub * 16];
        uint4 o1, o2;
        o1.x = packbf(fmaxf(dvi * f[0].x + bp[0], 0.f),  fmaxf(dvi * f[0].y + bp[1], 0.f));
        o1.y = packbf(fmaxf(dvi * f[1].x + bp[2], 0.f),  fmaxf(dvi * f[1].y + bp[3], 0.f));
        o1.z = packbf(fmaxf(dvi * f[2].x + bp[4], 0.f),  fmaxf(dvi * f[2].y + bp[5], 0.f));
        o1.w = packbf(fmaxf(dvi * f[3].x + bp[6], 0.f),  fmaxf(dvi * f[3].y + bp[7], 0.f));
        o2.x = packbf(fmaxf(dvi * f[4].x + bp[8], 0.f),  fmaxf(dvi * f[4].y + bp[9], 0.f));
        o2.y = packbf(fmaxf(dvi * f[5].x + bp[10], 0.f), fmaxf(dvi * f[5].y + bp[11], 0.f));
        o2.z = packbf(fmaxf(dvi * f[6].x + bp[12], 0.f), fmaxf(dvi * f[6].y + bp[13], 0.f));
        o2.w = packbf(fmaxf(dvi * f[7].x + bp[14], 0.f), fmaxf(dvi * f[7].y + bp[15], 0.f));
        outp[(size_t)node * 8 + sub * 2] = o1;
        outp[(size_t)node * 8 + sub * 2 + 1] = o2;
    }
}

// --------------------------- head (bf16 input, unchanged) ------------------

__global__ __launch_bounds__(256) void head_kernel(const unsigned* __restrict__ h,
                                                   const float* __restrict__ protos,
                                                   const float* __restrict__ Wf0,
                                                   const float* __restrict__ bf0,
                                                   const float* __restrict__ Wf1,
                                                   const float* __restrict__ bf1,
                                                   const int* __restrict__ y,
                                                   float* __restrict__ out, int N) {
    __shared__ float Hl[64 * 65];
    __shared__ float Pl[16 * 65];
    __shared__ float hh[64];
    __shared__ float pp[16];
    __shared__ float sim[64 * 17];
    __shared__ float Wf0l[128];
    __shared__ float bf0l[8];
    __shared__ float Wf1l[8];
    __shared__ float bf1l;
    int t = threadIdx.x;
    int n0 = blockIdx.x * 64;

    for (int idx = t; idx < 64 * 32; idx += 256) {
        int r = idx >> 5, c = idx & 31;
        int g = n0 + r;
        unsigned u = (g < N) ? h[(size_t)g * 32 + c] : 0u;
        float2 v = bpair(u);
        Hl[r * 65 + 2 * c] = v.x;
        Hl[r * 65 + 2 * c + 1] = v.y;
    }
    for (int idx = t; idx < 16 * 64; idx += 256) {
        int r = idx >> 6, c = idx & 63;
        Pl[r * 65 + c] = protos[idx];
    }
    if (t < 128) Wf0l[t] = Wf0[t];
    if (t < 8) { bf0l[t] = bf0[t]; Wf1l[t] = Wf1[t]; }
    if (t == 0) bf1l = bf1[0];
    __syncthreads();

    if (t < 64) {
        float s = 0.0f;
        for (int k = 0; k < 64; ++k) { float v = Hl[t * 65 + k]; s += v * v; }
        hh[t] = s;
    } else if (t < 80) {
        int p = t - 64;
        float s = 0.0f;
        for (int k = 0; k < 64; ++k) { float v = Pl[p * 65 + k]; s += v * v; }
        pp[p] = s;
    }
    __syncthreads();

    {
        int node = t & 63;
        int p4 = (t >> 6) * 4;
        float d0 = 0, d1 = 0, d2 = 0, d3 = 0;
        for (int k = 0; k < 64; ++k) {
            float hv = Hl[node * 65 + k];
            d0 += hv * Pl[(p4 + 0) * 65 + k];
            d1 += hv * Pl[(p4 + 1) * 65 + k];
            d2 += hv * Pl[(p4 + 2) * 65 + k];
            d3 += hv * Pl[(p4 + 3) * 65 + k];
        }
        float hhv = hh[node];
        float dd[4] = {d0, d1, d2, d3};
#pragma unroll
        for (int j = 0; j < 4; ++j) {
            float q = hhv + pp[p4 + j] - 2.0f * dd[j];
            q = q > 0.0f ? q : 0.0f;
            sim[node * 17 + p4 + j] = logf((q + 1.0f) / (q + 1e-4f));
        }
    }
    __syncthreads();

    if (t < 64) {
        int g = n0 + t;
        if (g < N) {
            float zacc = bf1l;
#pragma unroll
            for (int o = 0; o < 8; ++o) {
                float s = bf0l[o];
#pragma unroll
                for (int i2 = 0; i2 < 16; ++i2) s += sim[t * 17 + i2] * Wf0l[i2 * 8 + o];
                float gz = 0.5f * s * (1.0f + erff(s * 0.70710678118654752f));
                zacc += gz * Wf1l[o];
            }
            out[g] = 1.0f / (1.0f + expf(-zacc));
        }
    } else if (t < 128) {
        int g = n0 + (t - 64);
        if (g < N) out[N + g] = (float)y[g];
    }
}

// ---------------------------------------------------------------------------

extern "C" void kernel_launch(void* const* d_in, const int* in_sizes, int n_in,
                              void* d_out, int out_size, void* d_ws, size_t ws_size,
                              hipStream_t stream) {
    const float* x   = (const float*)d_in[0];
    const int*   ei  = (const int*)d_in[1];
    const int*   y   = (const int*)d_in[2];
    const float* W1  = (const float*)d_in[3];
    const float* b1  = (const float*)d_in[4];
    const float* W2  = (const float*)d_in[5];
    const float* b2  = (const float*)d_in[6];
    const float* W3  = (const float*)d_in[7];
    const float* b3  = (const float*)d_in[8];
    const float* pr  = (const float*)d_in[9];
    const float* Wf0 = (const float*)d_in[10];
    const float* bf0 = (const float*)d_in[11];
    const float* Wf1 = (const float*)d_in[12];
    const float* bf1 = (const float*)d_in[13];
    float* outp = (float*)d_out;

    const int N = in_sizes[2];       // 50000
    const int E = in_sizes[1] / 2;   // 800000
    const int NB = (N + BKT_NODES - 1) / BKT_NODES;   // 1563
    const int B = (E + EPB - 1) / EPB;                // 391 (<=512)

    char* w = (char*)d_ws;
    auto carve = [&](size_t bytes) {
        char* p = w;
        w += (bytes + 511) & ~(size_t)511;
        return p;
    };
    int*   glens   = (int*)carve((size_t)B * NB * 4);
    int*   gstart  = (int*)carve((size_t)B * NB * 4);
    int*   esort   = (int*)carve((size_t)B * EPB * 4);
    int*   row_beg = (int*)carve((size_t)N * 4);
    int*   row_end = (int*)carve((size_t)N * 4);
    float* dinv    = (float*)carve((size_t)N * 4);
    int*   csr     = (int*)carve((size_t)NB * LCAP * 4);
    __hip_bfloat16* Wp1 = (__hip_bfloat16*)carve(16384 * 2);
    __hip_bfloat16* Wp2 = (__hip_bfloat16*)carve(8192 * 2);
    __hip_bfloat16* Wp3 = (__hip_bfloat16*)carve(4096 * 2);
    unsigned char* T1b = (unsigned char*)carve((size_t)N * 128);   // e5m2
    unsigned char* T2b = (unsigned char*)carve((size_t)N * 64);    // e5m2
    unsigned char* T3b = (unsigned char*)carve((size_t)N * 64);    // e5m2
    __hip_bfloat16* bufH = (__hip_bfloat16*)carve((size_t)N * 128 * 2);

    size_t sort_lds = (size_t)(2 * NB + EPB) * 4;   // ~20.7 KB
    const int gemm1_blocks = (N + 63) / 64;          // 782
    const int agg_blocks = (N + 3) / 4;              // 12500

    // K1: bin+sort edges || pack weights
    sort_local_kernel<<<B + PREPB, 256, sort_lds, stream>>>(ei, E, NB, B, glens, gstart, esort,
                                                            W1, W2, W3, Wp1, Wp2, Wp3);
    // K2: CSR build || gemm1 (unscaled T1 -> fp8)
    csr_gemm1_kernel<<<NB + gemm1_blocks, 256, 0, stream>>>(esort, glens, gstart, NB, B, N,
                                                            row_beg, row_end, dinv, csr,
                                                            x, Wp1, T1b);
    // L1 aggregation (dinv gather, fp8 rows, 8 edges in flight) -> h1 bf16
    agg128_kernel<<<agg_blocks, 256, 0, stream>>>((const uint4*)T1b, b1, dinv, row_beg, row_end,
                                                  csr, (uint4*)bufH, N);
    // L2: gemm2 (prescaled T2 fp8); agg64 (16 edges in flight) -> h2 bf16
    mfma_gemm_kernel<128, 64><<<gemm1_blocks, 256, 0, stream>>>(bufH, Wp2, dinv, T2b, N);
    agg64_kernel<<<agg_blocks, 256, 0, stream>>>((const uint4*)T2b, b2, dinv, row_beg, row_end,
                                                 csr, (uint4*)bufH, N);
    // L3: gemm3 (prescaled T3 fp8); agg64 -> h3 bf16
    mfma_gemm_kernel<64, 64><<<gemm1_blocks, 256, 0, stream>>>(bufH, Wp3, dinv, T3b, N);
    agg64_kernel<<<agg_blocks, 256, 0, stream>>>((const uint4*)T3b, b3, dinv, row_beg, row_end,
                                                 csr, (uint4*)bufH, N);
    // Head
    head_kernel<<<(N + 63) / 64, 256, 0, stream>>>((const unsigned*)bufH, pr, Wf0, bf0, Wf1, bf1,
                                                   y, outp, N);
}

// Round 12
// 234.667 us; speedup vs baseline: 1.0243x; 1.0243x over previous
//
#include <hip/hip_runtime.h>
#include <hip/hip_bf16.h>
#include <hip/hip_fp16.h>
#include <math.h>

// ---------------------------------------------------------------------------
// SLADGNN round 12 = round-10 revert (best measured: 235.8us).
// fp8(e5m2) gather payloads; 16-lane/row agg128, 8-lane/row agg64 (r11's
// wider-ILP variant regressed -> aggs are issue-bound, not latency-bound).
// ---------------------------------------------------------------------------

typedef __attribute__((ext_vector_type(8))) short short8;
typedef __attribute__((ext_vector_type(4))) float f32x4;

#define BKT_SHIFT 5
#define BKT_NODES 32
#define EPB 2048        // edges per sort_local block (391 blocks)
#define LCAP 1024       // per-bucket CSR slot capacity (mean 512, +22 sigma)
#define PREPN 28672     // prep_w elements
#define PREPB 112       // prep_w blocks

__device__ __forceinline__ short f2bs(float x) {
    __hip_bfloat16 b = __float2bfloat16(x);
    return *reinterpret_cast<short*>(&b);
}
__device__ __forceinline__ float2 bpair(unsigned u) {
    float lo = __uint_as_float(u << 16);
    float hi = __uint_as_float(u & 0xffff0000u);
    return make_float2(lo, hi);
}
__device__ __forceinline__ unsigned packbf(float a, float b) {
    unsigned la = (unsigned)(unsigned short)f2bs(a);
    unsigned hb = (unsigned)(unsigned short)f2bs(b);
    return la | (hb << 16);
}

// ---- e5m2 helpers: e5m2 byte == high byte of f16 --------------------------
__device__ __forceinline__ unsigned short enc2_e5m2(float a, float b) {
    unsigned ua = __half_as_ushort(__float2half(a));
    unsigned ub = __half_as_ushort(__float2half(b));
    ua = (ua + 0x80u) >> 8;          // round-half-up on dropped byte
    ub = (ub + 0x80u) >> 8;
    return (unsigned short)((ua & 0xffu) | ((ub & 0xffu) << 8));
}
// bytes 0,1 of u -> half2
__device__ __forceinline__ __half2 dec2lo(unsigned u) {
    unsigned h = ((u & 0xffu) << 8) | ((u & 0xff00u) << 16);
    return *reinterpret_cast<__half2*>(&h);
}
// bytes 2,3 of u -> half2
__device__ __forceinline__ __half2 dec2hi(unsigned u) {
    unsigned h = ((u >> 8) & 0xff00u) | (u & 0xff000000u);
    return *reinterpret_cast<__half2*>(&h);
}
__device__ __forceinline__ __half2 h2shfl_xor(__half2 h, int m) {
    int i = *reinterpret_cast<int*>(&h);
    i = __shfl_xor(i, m, 64);
    return *reinterpret_cast<__half2*>(&i);
}

// Block-wide exclusive scan of arr[0..n) in LDS. 2 barriers per 256-chunk.
__device__ __forceinline__ void block_excl_scan(int* __restrict__ arr, int n, int t) {
    __shared__ int wsums[4];
    int lane = t & 63, wv = t >> 6;
    int carry = 0;
    for (int c0 = 0; c0 < n; c0 += 256) {
        int i = c0 + t;
        int v = (i < n) ? arr[i] : 0;
        int orig = v;
#pragma unroll
        for (int off = 1; off < 64; off <<= 1) {
            int u = __shfl_up(v, off, 64);
            if (lane >= off) v += u;
        }
        if (lane == 63) wsums[wv] = v;
        __syncthreads();
        int w0 = wsums[0], w1 = wsums[1], w2 = wsums[2], w3 = wsums[3];
        int woff = (wv > 0 ? w0 : 0) + (wv > 1 ? w1 : 0) + (wv > 2 ? w2 : 0);
        int tot = w0 + w1 + w2 + w3;
        __syncthreads();
        if (i < n) arr[i] = carry + woff + (v - orig);
        carry += tot;
    }
}

// --------------------- K1: sort_local || prep W1/W2/W3 ---------------------

__global__ __launch_bounds__(256) void sort_local_kernel(const int* __restrict__ ei, int E,
                                                         int NB, int B,
                                                         int* __restrict__ glens,
                                                         int* __restrict__ gstart,
                                                         int* __restrict__ edge_sorted,
                                                         const float* __restrict__ W1,
                                                         const float* __restrict__ W2,
                                                         const float* __restrict__ W3,
                                                         __hip_bfloat16* __restrict__ Wp1,
                                                         __hip_bfloat16* __restrict__ Wp2,
                                                         __hip_bfloat16* __restrict__ Wp3) {
    int t = threadIdx.x;
    if ((int)blockIdx.x >= B) {
        int i = ((int)blockIdx.x - B) * 256 + t;
        if (i < 16384) {                      // W1: 128x128
            int k = i >> 7, n = i & 127;
            Wp1[(((k >> 3) * 128) + n) * 8 + (k & 7)] = __float2bfloat16(W1[i]);
        } else if (i < 24576) {               // W2: 128x64
            int j = i - 16384;
            int k = j >> 6, n = j & 63;
            Wp2[(((k >> 3) * 64) + n) * 8 + (k & 7)] = __float2bfloat16(W2[j]);
        } else if (i < PREPN) {               // W3: 64x64
            int j = i - 24576;
            int k = j >> 6, n = j & 63;
            Wp3[(((k >> 3) * 64) + n) * 8 + (k & 7)] = __float2bfloat16(W3[j]);
        }
        return;
    }
    extern __shared__ int lds[];
    int* hist  = lds;                 // NB
    int* lbase = lds + NB;            // NB
    int* sortd = lds + 2 * NB;        // EPB
    int blk = blockIdx.x;
    int e0 = blk * EPB;
    int cnt = E - e0;
    if (cnt > EPB) cnt = EPB;

    for (int i = t; i < NB; i += 256) hist[i] = 0;
    __syncthreads();
    for (int i = t; i < cnt; i += 256) {
        int dst = ei[E + e0 + i];
        atomicAdd(&hist[dst >> BKT_SHIFT], 1);
    }
    __syncthreads();
    for (int i = t; i < NB; i += 256) lbase[i] = hist[i];
    __syncthreads();
    block_excl_scan(lbase, NB, t);
    __syncthreads();
    for (int i = t; i < NB; i += 256) {
        glens[(size_t)blk * NB + i] = hist[i];
        gstart[(size_t)blk * NB + i] = lbase[i];
    }
    __syncthreads();
    for (int i = t; i < cnt; i += 256) {
        int src = ei[e0 + i];
        int dst = ei[E + e0 + i];
        int pos = atomicAdd(&lbase[dst >> BKT_SHIFT], 1);
        sortd[pos] = (src << BKT_SHIFT) | (dst & (BKT_NODES - 1));
    }
    __syncthreads();
    for (int i = t; i < cnt; i += 256) edge_sorted[e0 + i] = sortd[i];
}

// --------------------- K2: csr_build || gemm1 (disjoint block ranges) ------
// gemm1 stores T1 as e5m2 bytes (unscaled).

__global__ __launch_bounds__(256) void csr_gemm1_kernel(const int* __restrict__ edge_sorted,
                                                        const int* __restrict__ glens,
                                                        const int* __restrict__ gstart,
                                                        int NB, int B, int N,
                                                        int* __restrict__ row_beg,
                                                        int* __restrict__ row_end,
                                                        float* __restrict__ dinv,
                                                        int* __restrict__ csr,
                                                        const float* __restrict__ X,
                                                        const __hip_bfloat16* __restrict__ Wp1,
                                                        unsigned char* __restrict__ T1) {
    int t = threadIdx.x;
    if ((int)blockIdx.x >= NB) {
        int bid = (int)blockIdx.x - NB;
        int lane = t & 63;
        int wave = t >> 6;
        int q = lane >> 4, l16 = lane & 15;
        int rbase = bid * 64 + wave * 16;
        int row = rbase + l16;
        int rowc = row < N ? row : N - 1;
        f32x4 acc[8];
#pragma unroll
        for (int i = 0; i < 8; ++i) acc[i] = (f32x4){0.f, 0.f, 0.f, 0.f};
#pragma unroll
        for (int kt = 0; kt < 4; ++kt) {
            int k0 = kt * 32 + q * 8;
            const float* ap = X + (size_t)rowc * 128 + k0;
            float4 lo = *(const float4*)ap;
            float4 hi = *(const float4*)(ap + 4);
            short8 afrag;
            afrag[0] = f2bs(lo.x); afrag[1] = f2bs(lo.y);
            afrag[2] = f2bs(lo.z); afrag[3] = f2bs(lo.w);
            afrag[4] = f2bs(hi.x); afrag[5] = f2bs(hi.y);
            afrag[6] = f2bs(hi.z); afrag[7] = f2bs(hi.w);
            const short8* wrow = (const short8*)(Wp1 + (size_t)(kt * 4 + q) * 128 * 8);
#pragma unroll
            for (int tt = 0; tt < 8; ++tt) {
                short8 bfrag = wrow[tt * 16 + l16];
                acc[tt] = __builtin_amdgcn_mfma_f32_16x16x32_bf16(afrag, bfrag, acc[tt], 0, 0, 0);
            }
        }
        // epilogue: pair adjacent cols (l16, l16^1) via shfl, even lanes store u16
#pragma unroll
        for (int r = 0; r < 4; ++r) {
            int gr = rbase + q * 4 + r;
#pragma unroll
            for (int tt = 0; tt < 8; ++tt) {
                float v = acc[tt][r];
                float p = __shfl_xor(v, 1, 64);
                if (((l16 & 1) == 0) && gr < N)
                    *(unsigned short*)(T1 + (size_t)gr * 128 + tt * 16 + l16) = enc2_e5m2(v, p);
            }
        }
        return;
    }
    // ---- csr_build ----
    __shared__ int lruns[512];
    __shared__ int loffs[512];
    __shared__ int sdeg[BKT_NODES];
    __shared__ int scur[BKT_NODES];
    __shared__ int raw[LCAP];
    __shared__ int srt[LCAP];
    int b = blockIdx.x;

    for (int i = t; i < 512; i += 256) {
        int v = (i < B) ? glens[(size_t)i * NB + b] : 0;
        lruns[i] = v;
        loffs[i] = v;
    }
    if (t < BKT_NODES) sdeg[t] = 0;
    __syncthreads();
    block_excl_scan(loffs, B, t);
    __syncthreads();
    int cnt = loffs[B - 1] + lruns[B - 1];
    if (cnt > LCAP) cnt = LCAP;

    for (int r = t; r < B; r += 256) {
        int len = lruns[r];
        if (len) {
            int off = loffs[r];
            int st = r * EPB + gstart[(size_t)r * NB + b];
            for (int k = 0; k < len; ++k) {
                int p = off + k;
                if (p < LCAP) raw[p] = edge_sorted[st + k];
            }
        }
    }
    __syncthreads();
    for (int i = t; i < cnt; i += 256) atomicAdd(&sdeg[raw[i] & (BKT_NODES - 1)], 1);
    __syncthreads();
    int base = b * LCAP;
    if (t < BKT_NODES) {
        int ssum = 0;
        for (int i = 0; i < t; ++i) ssum += sdeg[i];
        scur[t] = ssum;
        int node = b * BKT_NODES + t;
        if (node < N) {
            row_beg[node] = base + ssum;
            row_end[node] = base + ssum + sdeg[t];
            dinv[node] = rsqrtf((float)(sdeg[t] + 1));   // +1 self loop
        }
    }
    __syncthreads();
    for (int i = t; i < cnt; i += 256) {
        int p = raw[i];
        int pos = atomicAdd(&scur[p & (BKT_NODES - 1)], 1);
        srt[pos] = p >> BKT_SHIFT;
    }
    __syncthreads();
    for (int i = t; i < cnt; i += 256) csr[base + i] = srt[i];
}

// --------------------------- MFMA GEMM (fp8 out, prescaled) ----------------
// C[r][:] = e5m2( dinv[r] * (A[r][:] @ W) )   A bf16.

template <int DI, int DO>
__global__ __launch_bounds__(256) void mfma_gemm_kernel(const __hip_bfloat16* __restrict__ A,
                                                        const __hip_bfloat16* __restrict__ Wp,
                                                        const float* __restrict__ dinv,
                                                        unsigned char* __restrict__ C, int N) {
    constexpr int NT = DO / 16;
    int t = threadIdx.x;
    int wave = t >> 6, lane = t & 63;
    int q = lane >> 4, l16 = lane & 15;
    int rbase = blockIdx.x * 64 + wave * 16;
    int row = rbase + l16;
    int rowc = row < N ? row : N - 1;

    f32x4 acc[NT];
#pragma unroll
    for (int i = 0; i < NT; ++i) acc[i] = (f32x4){0.f, 0.f, 0.f, 0.f};

#pragma unroll
    for (int kt = 0; kt < DI / 32; ++kt) {
        int k0 = kt * 32 + q * 8;
        short8 afrag = *(const short8*)(A + (size_t)rowc * DI + k0);
        const short8* wrow = (const short8*)(Wp + (size_t)(kt * 4 + q) * DO * 8);
#pragma unroll
        for (int tt = 0; tt < NT; ++tt) {
            short8 bfrag = wrow[tt * 16 + l16];
            acc[tt] = __builtin_amdgcn_mfma_f32_16x16x32_bf16(afrag, bfrag, acc[tt], 0, 0, 0);
        }
    }
#pragma unroll
    for (int r = 0; r < 4; ++r) {
        int gr = rbase + q * 4 + r;
        float dv = dinv[gr < N ? gr : 0];
#pragma unroll
        for (int tt = 0; tt < NT; ++tt) {
            float v = acc[tt][r] * dv;
            float p = __shfl_xor(v, 1, 64);
            if (((l16 & 1) == 0) && gr < N)
                *(unsigned short*)(C + (size_t)gr * DO + tt * 16 + l16) = enc2_e5m2(v, p);
        }
    }
}

// --------------------------- aggregation (fp8 gathers) ---------------------

// D=128 e5m2 rows (128B), UNSCALED: gathers dinv[src]. quarter-wave/edge,
// 16 lanes x uint2 (8 feats). half2 accumulate; bf16 output.
__global__ __launch_bounds__(256) void agg128_kernel(const uint2* __restrict__ tmp,
                                                     const float* __restrict__ bias,
                                                     const float* __restrict__ dinv,
                                                     const int* __restrict__ row_beg,
                                                     const int* __restrict__ row_end,
                                                     const int* __restrict__ csr_src,
                                                     uint4* __restrict__ outp, int N) {
    int lane = threadIdx.x & 63;
    int q = lane >> 4, sub = lane & 15;
    int node = blockIdx.x * 4 + (threadIdx.x >> 6);
    if (node >= N) return;
    float dvi = dinv[node];
    __half2 c01 = __float2half2_rn(0.f), c23 = c01, c45 = c01, c67 = c01;
    if (q == 0) {
        uint2 sv = tmp[(size_t)node * 16 + sub];
        __half2 dv2 = __float2half2_rn(dvi);
        c01 = __hmul2(dec2lo(sv.x), dv2);
        c23 = __hmul2(dec2hi(sv.x), dv2);
        c45 = __hmul2(dec2lo(sv.y), dv2);
        c67 = __hmul2(dec2hi(sv.y), dv2);
    }
    int beg = row_beg[node], end = row_end[node];
    for (int j = beg; j < end; j += 64) {
        int m = end - j;
        if (m > 64) m = 64;
        int s = 0;
        float dv = 0.0f;
        if (lane < m) { s = csr_src[j + lane]; dv = dinv[s]; }
        int iters = (m + 3) >> 2;
        for (int k = 0; k < iters; ++k) {
            int e = 4 * k + q;
            int ec = (e < m) ? e : 0;
            int sk = __shfl(s, ec, 64);
            float dkf = __shfl(dv, ec, 64);
            uint2 v = tmp[(size_t)sk * 16 + sub];
            __half2 dk2 = __float2half2_rn((e < m) ? dkf : 0.0f);
            c01 = __hfma2(dec2lo(v.x), dk2, c01);
            c23 = __hfma2(dec2hi(v.x), dk2, c23);
            c45 = __hfma2(dec2lo(v.y), dk2, c45);
            c67 = __hfma2(dec2hi(v.y), dk2, c67);
        }
    }
#pragma unroll
    for (int off = 16; off <= 32; off <<= 1) {
        c01 = __hadd2(c01, h2shfl_xor(c01, off));
        c23 = __hadd2(c23, h2shfl_xor(c23, off));
        c45 = __hadd2(c45, h2shfl_xor(c45, off));
        c67 = __hadd2(c67, h2shfl_xor(c67, off));
    }
    if (q == 0) {
        float2 f01 = __half22float2(c01);
        float2 f23 = __half22float2(c23);
        float2 f45 = __half22float2(c45);
        float2 f67 = __half22float2(c67);
        float4 b0 = *(const float4*)&bias[sub * 8];
        float4 b1 = *(const float4*)&bias[sub * 8 + 4];
        uint4 o;
        o.x = packbf(fmaxf(dvi * f01.x + b0.x, 0.f), fmaxf(dvi * f01.y + b0.y, 0.f));
        o.y = packbf(fmaxf(dvi * f23.x + b0.z, 0.f), fmaxf(dvi * f23.y + b0.w, 0.f));
        o.z = packbf(fmaxf(dvi * f45.x + b1.x, 0.f), fmaxf(dvi * f45.y + b1.y, 0.f));
        o.w = packbf(fmaxf(dvi * f67.x + b1.z, 0.f), fmaxf(dvi * f67.y + b1.w, 0.f));
        outp[(size_t)node * 16 + sub] = o;
    }
}

// D=64 e5m2 rows (64B), PRESCALED. eighth-wave/edge, 8 lanes x uint2.
__global__ __launch_bounds__(256) void agg64_kernel(const uint2* __restrict__ tmp,
                                                    const float* __restrict__ bias,
                                                    const float* __restrict__ dinv,
                                                    const int* __restrict__ row_beg,
                                                    const int* __restrict__ row_end,
                                                    const int* __restrict__ csr_src,
                                                    uint4* __restrict__ outp, int N) {
    int lane = threadIdx.x & 63;
    int o8 = lane >> 3, sub = lane & 7;
    int node = blockIdx.x * 4 + (threadIdx.x >> 6);
    if (node >= N) return;
    float dvi = dinv[node];
    __half2 one2 = __float2half2_rn(1.f);
    __half2 zero2 = __float2half2_rn(0.f);
    __half2 c01 = zero2, c23 = zero2, c45 = zero2, c67 = zero2;
    if (o8 == 0) {
        uint2 sv = tmp[(size_t)node * 8 + sub];
        c01 = dec2lo(sv.x);
        c23 = dec2hi(sv.x);
        c45 = dec2lo(sv.y);
        c67 = dec2hi(sv.y);
    }
    int beg = row_beg[node], end = row_end[node];
    for (int j = beg; j < end; j += 64) {
        int m = end - j;
        if (m > 64) m = 64;
        int s = (lane < m) ? csr_src[j + lane] : 0;
        int iters = (m + 7) >> 3;
        for (int k = 0; k < iters; ++k) {
            int e = 8 * k + o8;
            int ec = (e < m) ? e : 0;
            int sk = __shfl(s, ec, 64);
            uint2 v = tmp[(size_t)sk * 8 + sub];
            __half2 dk2 = (e < m) ? one2 : zero2;
            c01 = __hfma2(dec2lo(v.x), dk2, c01);
            c23 = __hfma2(dec2hi(v.x), dk2, c23);
            c45 = __hfma2(dec2lo(v.y), dk2, c45);
            c67 = __hfma2(dec2hi(v.y), dk2, c67);
        }
    }
#pragma unroll
    for (int off = 8; off <= 32; off <<= 1) {
        c01 = __hadd2(c01, h2shfl_xor(c01, off));
        c23 = __hadd2(c23, h2shfl_xor(c23, off));
        c45 = __hadd2(c45, h2shfl_xor(c45, off));
        c67 = __hadd2(c67, h2shfl_xor(c67, off));
    }
    if (o8 == 0) {
        float2 f01 = __half22float2(c01);
        float2 f23 = __half22float2(c23);
        float2 f45 = __half22float2(c45);
        float2 f67 = __half22float2(c67);
        float4 b0 = *(const float4*)&bias[sub * 8];
        float4 b1 = *(const float4*)&bias[sub * 8 + 4];
        uint4 o;
        o.x = packbf(fmaxf(dvi * f01.x + b0.x, 0.f), fmaxf(dvi * f01.y + b0.y, 0.f));
        o.y = packbf(fmaxf(dvi * f23.x + b0.z, 0.f), fmaxf(dvi * f23.y + b0.w, 0.f));
        o.z = packbf(fmaxf(dvi * f45.x + b1.x, 0.f), fmaxf(dvi * f45.y + b1.y, 0.f));
        o.w = packbf(fmaxf(dvi * f67.x + b1.z, 0.f), fmaxf(dvi * f67.y + b1.w, 0.f));
        outp[(size_t)node * 8 + sub] = o;
    }
}

// --------------------------- head (bf16 input) -----------------------------

__global__ __launch_bounds__(256) void head_kernel(const unsigned* __restrict__ h,
                                                   const float* __restrict__ protos,
                                                   const float* __restrict__ Wf0,
                                                   const float* __restrict__ bf0,
                                                   const float* __restrict__ Wf1,
                                                   const float* __restrict__ bf1,
                                                   const int* __restrict__ y,
                                                   float* __restrict__ out, int N) {
    __shared__ float Hl[64 * 65];
    __shared__ float Pl[16 * 65];
    __shared__ float hh[64];
    __shared__ float pp[16];
    __shared__ float sim[64 * 17];
    __shared__ float Wf0l[128];
    __shared__ float bf0l[8];
    __shared__ float Wf1l[8];
    __shared__ float bf1l;
    int t = threadIdx.x;
    int n0 = blockIdx.x * 64;

    for (int idx = t; idx < 64 * 32; idx += 256) {
        int r = idx >> 5, c = idx & 31;
        int g = n0 + r;
        unsigned u = (g < N) ? h[(size_t)g * 32 + c] : 0u;
        float2 v = bpair(u);
        Hl[r * 65 + 2 * c] = v.x;
        Hl[r * 65 + 2 * c + 1] = v.y;
    }
    for (int idx = t; idx < 16 * 64; idx += 256) {
        int r = idx >> 6, c = idx & 63;
        Pl[r * 65 + c] = protos[idx];
    }
    if (t < 128) Wf0l[t] = Wf0[t];
    if (t < 8) { bf0l[t] = bf0[t]; Wf1l[t] = Wf1[t]; }
    if (t == 0) bf1l = bf1[0];
    __syncthreads();

    if (t < 64) {
        float s = 0.0f;
        for (int k = 0; k < 64; ++k) { float v = Hl[t * 65 + k]; s += v * v; }
        hh[t] = s;
    } else if (t < 80) {
        int p = t - 64;
        float s = 0.0f;
        for (int k = 0; k < 64; ++k) { float v = Pl[p * 65 + k]; s += v * v; }
        pp[p] = s;
    }
    __syncthreads();

    {
        int node = t & 63;
        int p4 = (t >> 6) * 4;
        float d0 = 0, d1 = 0, d2 = 0, d3 = 0;
        for (int k = 0; k < 64; ++k) {
            float hv = Hl[node * 65 + k];
            d0 += hv * Pl[(p4 + 0) * 65 + k];
            d1 += hv * Pl[(p4 + 1) * 65 + k];
            d2 += hv * Pl[(p4 + 2) * 65 + k];
            d3 += hv * Pl[(p4 + 3) * 65 + k];
        }
        float hhv = hh[node];
        float dd[4] = {d0, d1, d2, d3};
#pragma unroll
        for (int j = 0; j < 4; ++j) {
            float q = hhv + pp[p4 + j] - 2.0f * dd[j];
            q = q > 0.0f ? q : 0.0f;
            sim[node * 17 + p4 + j] = logf((q + 1.0f) / (q + 1e-4f));
        }
    }
    __syncthreads();

    if (t < 64) {
        int g = n0 + t;
        if (g < N) {
            float zacc = bf1l;
#pragma unroll
            for (int o = 0; o < 8; ++o) {
                float s = bf0l[o];
#pragma unroll
                for (int i2 = 0; i2 < 16; ++i2) s += sim[t * 17 + i2] * Wf0l[i2 * 8 + o];
                float gz = 0.5f * s * (1.0f + erff(s * 0.70710678118654752f));
                zacc += gz * Wf1l[o];
            }
            out[g] = 1.0f / (1.0f + expf(-zacc));
        }
    } else if (t < 128) {
        int g = n0 + (t - 64);
        if (g < N) out[N + g] = (float)y[g];
    }
}

// ---------------------------------------------------------------------------

extern "C" void kernel_launch(void* const* d_in, const int* in_sizes, int n_in,
                              void* d_out, int out_size, void* d_ws, size_t ws_size,
                              hipStream_t stream) {
    const float* x   = (const float*)d_in[0];
    const int*   ei  = (const int*)d_in[1];
    const int*   y   = (const int*)d_in[2];
    const float* W1  = (const float*)d_in[3];
    const float* b1  = (const float*)d_in[4];
    const float* W2  = (const float*)d_in[5];
    const float* b2  = (const float*)d_in[6];
    const float* W3  = (const float*)d_in[7];
    const float* b3  = (const float*)d_in[8];
    const float* pr  = (const float*)d_in[9];
    const float* Wf0 = (const float*)d_in[10];
    const float* bf0 = (const float*)d_in[11];
    const float* Wf1 = (const float*)d_in[12];
    const float* bf1 = (const float*)d_in[13];
    float* outp = (float*)d_out;

    const int N = in_sizes[2];       // 50000
    const int E = in_sizes[1] / 2;   // 800000
    const int NB = (N + BKT_NODES - 1) / BKT_NODES;   // 1563
    const int B = (E + EPB - 1) / EPB;                // 391 (<=512)

    char* w = (char*)d_ws;
    auto carve = [&](size_t bytes) {
        char* p = w;
        w += (bytes + 511) & ~(size_t)511;
        return p;
    };
    int*   glens   = (int*)carve((size_t)B * NB * 4);
    int*   gstart  = (int*)carve((size_t)B * NB * 4);
    int*   esort   = (int*)carve((size_t)B * EPB * 4);
    int*   row_beg = (int*)carve((size_t)N * 4);
    int*   row_end = (int*)carve((size_t)N * 4);
    float* dinv    = (float*)carve((size_t)N * 4);
    int*   csr     = (int*)carve((size_t)NB * LCAP * 4);
    __hip_bfloat16* Wp1 = (__hip_bfloat16*)carve(16384 * 2);
    __hip_bfloat16* Wp2 = (__hip_bfloat16*)carve(8192 * 2);
    __hip_bfloat16* Wp3 = (__hip_bfloat16*)carve(4096 * 2);
    unsigned char* T1b = (unsigned char*)carve((size_t)N * 128);   // e5m2
    unsigned char* T2b = (unsigned char*)carve((size_t)N * 64);    // e5m2
    unsigned char* T3b = (unsigned char*)carve((size_t)N * 64);    // e5m2
    __hip_bfloat16* bufH = (__hip_bfloat16*)carve((size_t)N * 128 * 2);

    size_t sort_lds = (size_t)(2 * NB + EPB) * 4;   // ~20.7 KB
    const int gemm1_blocks = (N + 63) / 64;          // 782
    const int agg_blocks = (N + 3) / 4;              // 12500

    // K1: bin+sort edges || pack weights
    sort_local_kernel<<<B + PREPB, 256, sort_lds, stream>>>(ei, E, NB, B, glens, gstart, esort,
                                                            W1, W2, W3, Wp1, Wp2, Wp3);
    // K2: CSR build || gemm1 (unscaled T1 -> fp8)
    csr_gemm1_kernel<<<NB + gemm1_blocks, 256, 0, stream>>>(esort, glens, gstart, NB, B, N,
                                                            row_beg, row_end, dinv, csr,
                                                            x, Wp1, T1b);
    // L1 aggregation (dinv gather, fp8 rows) -> h1 bf16 in bufH
    agg128_kernel<<<agg_blocks, 256, 0, stream>>>((const uint2*)T1b, b1, dinv, row_beg, row_end,
                                                  csr, (uint4*)bufH, N);
    // L2: gemm2 (prescaled T2 fp8); agg64 -> h2 bf16 in bufH
    mfma_gemm_kernel<128, 64><<<gemm1_blocks, 256, 0, stream>>>(bufH, Wp2, dinv, T2b, N);
    agg64_kernel<<<agg_blocks, 256, 0, stream>>>((const uint2*)T2b, b2, dinv, row_beg, row_end,
                                                 csr, (uint4*)bufH, N);
    // L3: gemm3 (prescaled T3 fp8); agg64 -> h3 bf16
    mfma_gemm_kernel<64, 64><<<gemm1_blocks, 256, 0, stream>>>(bufH, Wp3, dinv, T3b, N);
    agg64_kernel<<<agg_blocks, 256, 0, stream>>>((const uint2*)T3b, b3, dinv, row_beg, row_end,
                                                 csr, (uint4*)bufH, N);
    // Head
    head_kernel<<<(N + 63) / 64, 256, 0, stream>>>((const unsigned*)bufH, pr, Wf0, bf0, Wf1, bf1,
                                                   y, outp, N);
}